// Round 3
// baseline (307.597 us; speedup 1.0000x reference)
//
#include <hip/hip_runtime.h>

// Problem: B=2, S=2048, DIM=1024, H=16, DH=64. I/O fp32; internals bf16 MFMA.
#define Bn   2
#define Sn   2048
#define DIMn 1024
#define Hn   16
#define DHn  64

typedef unsigned short u16;
typedef unsigned int   u32;

typedef __attribute__((ext_vector_type(8))) __bf16 bf16x8;
typedef __attribute__((ext_vector_type(8))) float  f32x8v;
typedef __attribute__((ext_vector_type(4))) float  f32x4;

__device__ __forceinline__ u16 f2bf(float f) {
    union { float f; u32 u; } v; v.f = f;
    u32 r = v.u + 0x7fffu + ((v.u >> 16) & 1u);  // RNE
    return (u16)(r >> 16);
}
__device__ __forceinline__ bf16x8 ldfrag(const u16* p) {
    union { uint4 u; bf16x8 v; } x;
    x.u = *(const uint4*)p;
    return x.v;
}
__device__ __forceinline__ uint4 pack8(const u16 h[8]) {
    uint4 r;
    r.x = (u32)h[0] | ((u32)h[1] << 16);
    r.y = (u32)h[2] | ((u32)h[3] << 16);
    r.z = (u32)h[4] | ((u32)h[5] << 16);
    r.w = (u32)h[6] | ((u32)h[7] << 16);
    return r;
}
// async 16B global->LDS: lds dest = wave-uniform base + lane*16; global src PER-LANE
__device__ __forceinline__ void gl_lds16(const void* g, void* l) {
    __builtin_amdgcn_global_load_lds(
        (const __attribute__((address_space(1))) void*)g,
        (__attribute__((address_space(3))) void*)l, 16, 0, 0);
}
// raw barrier with compiler-level memory fences on both sides (no vmcnt drain)
__device__ __forceinline__ void barrier_nodrain() {
    asm volatile("" ::: "memory");
    __builtin_amdgcn_s_barrier();
    asm volatile("" ::: "memory");
}

// ---------------------------------------------------------------------------
// Prep: transpose+convert the 4 fp32 weights [k][n] -> bf16 Wt[n][k].
// ---------------------------------------------------------------------------
__global__ __launch_bounds__(256) void prep_weights(
    const float* __restrict__ Wq, const float* __restrict__ Wk,
    const float* __restrict__ Wv, const float* __restrict__ Wf,
    u16* __restrict__ Wt)
{
    __shared__ __align__(16) float tile[64][68];
    const float* W = (blockIdx.z == 0) ? Wq : (blockIdx.z == 1) ? Wk
                   : (blockIdx.z == 2) ? Wv : Wf;
    u16* out = Wt + (size_t)blockIdx.z * DIMn * DIMn;
    const int t = threadIdx.x;
    const int n0 = blockIdx.x * 64, k0 = blockIdx.y * 64;
    const int rr = t >> 4, cc = (t & 15) * 4;
#pragma unroll
    for (int i = 0; i < 4; i++)
        *(float4*)&tile[rr + 16 * i][cc] =
            *(const float4*)(W + (size_t)(k0 + rr + 16 * i) * DIMn + n0 + cc);
    __syncthreads();
#pragma unroll
    for (int e = 0; e < 2; e++) {
        const int ci = 2 * t + e;
        const int n = ci >> 3, kc = ci & 7;
        u16 h[8];
#pragma unroll
        for (int j = 0; j < 8; j++) h[j] = f2bf(tile[kc * 8 + j][n]);
        *(uint4*)(out + (size_t)(n0 + n) * DIMn + k0 + kc * 8) = pack8(h);
    }
}

// ---------------------------------------------------------------------------
// Fused QKV GEMM, pipelined (depth-2, counted vmcnt, raw barriers).
// Per wave per K-tile: 4 A-chunk + 2 B-chunk global_load_lds = 6 vmcnt ops.
// Steady state: 12 outstanding -> s_waitcnt vmcnt(6) completes tile t while
// tile t+1 stays in flight across the barrier (T3+T4).
// ---------------------------------------------------------------------------
__global__ __launch_bounds__(256) void gemm_qkv(
    const float* __restrict__ Aq, const float* __restrict__ Ak,
    const float* __restrict__ Av, const u16* __restrict__ Wt,
    const float* __restrict__ bqp, const float* __restrict__ bkp,
    const float* __restrict__ bvp, u16* __restrict__ Qw,
    u16* __restrict__ Kw, u16* __restrict__ VwT)
{
    __shared__ union {
        struct { __align__(16) float Afp[2][64 * 64];    // 2 x 16 KB, chunked
                 __align__(16) u16   Bbf[2][32 * 128]; } s;  // 2 x 8 KB, chunked
        __align__(16) u16 Ep[32][144];                   // epilogue staging
    } L;

    // ---- XCD-aware swizzle: f = xcd + 8*(x + 8*(yi + 4*z)) ----
    const int f = blockIdx.x;
    const int xcd = f & 7;
    const int q = f >> 3;
    const int z = q >> 5;
    const int rem = q & 31;
    const int yi = rem >> 3, x = rem & 7;
    const int y = xcd * 4 + yi;
    const int m0 = y * 128, n0 = x * 128;

    const float* A    = (z == 0) ? Aq  : (z == 1) ? Ak  : Av;
    const float* bias = (z == 0) ? bqp : (z == 1) ? bkp : bvp;
    const u16* Bt = Wt + (size_t)z * DIMn * DIMn;

    const int t = threadIdx.x;
    const int lane = t & 63, wave = t >> 6;
    const int quad = lane >> 4, l15 = lane & 15;
    const int wm = wave >> 1, wn = wave & 1;

    // Per-s staging base pointers (k0-invariant part)
    const float* baseA[4];
#pragma unroll
    for (int s = 0; s < 4; s++) {
        const int c = wave * 16 + s * 4 + quad;
        const int g = c >> 3, qq = (c >> 1) & 3, h = c & 1;
        baseA[s] = A + (size_t)(m0 + g * 16 + l15) * DIMn + qq * 8 + h * 4;
    }
    const u16* baseB[2];
#pragma unroll
    for (int s = 0; s < 2; s++) {
        const int c = wave * 8 + s * 4 + quad;
        const int jg = c >> 2, qq = c & 3;
        baseB[s] = Bt + (size_t)(n0 + jg * 16 + l15) * DIMn + qq * 8;
    }

    auto STAGE = [&](int tt, int buf) {
        const int k0 = tt * 32;
#pragma unroll
        for (int s = 0; s < 4; s++)
            gl_lds16(baseA[s] + k0, &L.s.Afp[buf][(wave * 16 + s * 4) * 64]);
#pragma unroll
        for (int s = 0; s < 2; s++)
            gl_lds16(baseB[s] + k0, &L.s.Bbf[buf][(wave * 8 + s * 4) * 128]);
    };

    f32x4 acc[4][4];
#pragma unroll
    for (int i = 0; i < 4; i++)
#pragma unroll
        for (int j = 0; j < 4; j++) acc[i][j] = (f32x4){0.f, 0.f, 0.f, 0.f};

    const int NT = DIMn / 32;  // 32
    STAGE(0, 0);
    STAGE(1, 1);

#pragma unroll 2
    for (int tt = 0; tt < NT; ++tt) {
        const int buf = tt & 1;
        // complete tile tt's own 6 loads; keep tile tt+1's 6 in flight
        if (tt < NT - 1) asm volatile("s_waitcnt vmcnt(6)" ::: "memory");
        else             asm volatile("s_waitcnt vmcnt(0)" ::: "memory");
        barrier_nodrain();  // all waves' tile-tt data visible

        bf16x8 a[4], b[4];
#pragma unroll
        for (int i = 0; i < 4; i++) {
            const int g = wm * 4 + i;
            union { struct { f32x4 lo, hi; } p; f32x8v v; } u;
            u.p.lo = *(const f32x4*)&L.s.Afp[buf][(g * 8 + quad * 2 + 0) * 64 + l15 * 4];
            u.p.hi = *(const f32x4*)&L.s.Afp[buf][(g * 8 + quad * 2 + 1) * 64 + l15 * 4];
            a[i] = __builtin_convertvector(u.v, bf16x8);
        }
#pragma unroll
        for (int j = 0; j < 4; j++)
            b[j] = ldfrag(&L.s.Bbf[buf][((wn * 4 + j) * 4 + quad) * 128 + l15 * 8]);
#pragma unroll
        for (int i = 0; i < 4; i++)
#pragma unroll
            for (int j = 0; j < 4; j++)
                acc[i][j] = __builtin_amdgcn_mfma_f32_16x16x32_bf16(a[i], b[j], acc[i][j], 0, 0, 0);

        // ensure this wave's LDS reads are complete before signalling the
        // freeing barrier (s_barrier does NOT drain lgkmcnt)
        asm volatile("s_waitcnt lgkmcnt(0)" ::: "memory");
        barrier_nodrain();  // all waves done reading buf
        if (tt + 2 < NT) STAGE(tt + 2, buf);  // refill just-freed buffer
    }

    float bv[4];
#pragma unroll
    for (int j = 0; j < 4; j++) bv[j] = bias[n0 + wn * 64 + j * 16 + l15];

    const int bb = y >> 4;

    if (z < 2) {
        // ---- split [b,h,s,d]: phase over i (32 m-rows x 128 n per phase) ----
        u16* out = (z == 0) ? Qw : Kw;
#pragma unroll
        for (int i = 0; i < 4; i++) {
            __syncthreads();
#pragma unroll
            for (int j = 0; j < 4; j++)
#pragma unroll
                for (int r = 0; r < 4; r++)
                    L.Ep[wm * 16 + quad * 4 + r][wn * 64 + j * 16 + l15] =
                        f2bf(acc[i][j][r] + bv[j]);
            __syncthreads();
#pragma unroll
            for (int e = 0; e < 2; e++) {
                const int ci = t + 256 * e;
                const int row = ci >> 4, c = ci & 15;
                const uint4 v = *(const uint4*)&L.Ep[row][c * 8];
                const int m = m0 + (row >> 4) * 64 + i * 16 + (row & 15);
                const int ss = m & 2047;
                const int n = n0 + c * 8;
                const int hh = n >> 6, dd = n & 63;
                *(uint4*)(out + ((size_t)(bb * Hn + hh) * Sn + ss) * DHn + dd) = v;
            }
        }
    } else {
        // ---- transposed [b,h,d,s]: phase over j (32 n-rows x 128 m) ----
#pragma unroll
        for (int j = 0; j < 4; j++) {
            __syncthreads();
#pragma unroll
            for (int i = 0; i < 4; i++) {
                u16 h4[4];
#pragma unroll
                for (int r = 0; r < 4; r++) h4[r] = f2bf(acc[i][j][r] + bv[j]);
                uint2 pk;
                pk.x = (u32)h4[0] | ((u32)h4[1] << 16);
                pk.y = (u32)h4[2] | ((u32)h4[3] << 16);
                *(uint2*)&L.Ep[wn * 16 + l15][wm * 64 + i * 16 + quad * 4] = pk;
            }
            __syncthreads();
#pragma unroll
            for (int e = 0; e < 2; e++) {
                const int ci = t + 256 * e;
                const int row = ci >> 4, c = ci & 15;
                const uint4 v = *(const uint4*)&L.Ep[row][c * 8];
                const int n = n0 + (row >> 4) * 64 + j * 16 + (row & 15);
                const int hh = n >> 6, dd = n & 63;
                const int ss = (m0 & 2047) + c * 8;
                *(uint4*)(VwT + ((size_t)(bb * Hn + hh) * DHn + dd) * Sn + ss) = v;
            }
        }
    }
}

// ---------------------------------------------------------------------------
// Final GEMM, pipelined depth-3 (only 1 block/CU -> deepest pipeline).
// Per wave per tile: 2 A + 2 B = 4 vmcnt ops; steady 12 outstanding ->
// s_waitcnt vmcnt(8) keeps two tiles in flight.
// ---------------------------------------------------------------------------
__global__ __launch_bounds__(256) void gemm_final(
    const u16* __restrict__ A, const u16* __restrict__ Bt,
    const float* __restrict__ bias, float* __restrict__ out)
{
    __shared__ __align__(16) u16 Abf[3][32 * 128];  // 3 x 8 KB chunked
    __shared__ __align__(16) u16 Bbf[3][32 * 128];  // 3 x 8 KB chunked

    const int f = blockIdx.x;
    const int xcd = f & 7, q = f >> 3;
    const int y = xcd * 4 + (q >> 3), x = q & 7;
    const int m0 = y * 128, n0 = x * 128;

    const int t = threadIdx.x;
    const int lane = t & 63, wave = t >> 6;
    const int quad = lane >> 4, l15 = lane & 15;
    const int wm = wave >> 1, wn = wave & 1;

    int arow[2], aq[2];
#pragma unroll
    for (int s = 0; s < 2; s++) {
        const int c = wave * 8 + s * 4 + quad;
        arow[s] = (c >> 2) * 16 + l15;  // local m row
        aq[s] = c & 3;
    }
    const u16* baseB[2];
#pragma unroll
    for (int s = 0; s < 2; s++) {
        const int c = wave * 8 + s * 4 + quad;
        baseB[s] = Bt + (size_t)(n0 + (c >> 2) * 16 + l15) * DIMn + (c & 3) * 8;
    }

    auto STAGE = [&](int tt, int buf) {
        const int hh = tt >> 1, d64 = (tt & 1) * 32;
#pragma unroll
        for (int s = 0; s < 2; s++) {
            const int m = m0 + arow[s], bb = m >> 11, ss = m & 2047;
            const u16* gp = A + ((size_t)(bb * Hn + hh) * Sn + ss) * DHn + d64 + aq[s] * 8;
            gl_lds16(gp, &Abf[buf][(wave * 8 + s * 4) * 128]);
        }
#pragma unroll
        for (int s = 0; s < 2; s++)
            gl_lds16(baseB[s] + tt * 32, &Bbf[buf][(wave * 8 + s * 4) * 128]);
    };

    f32x4 acc[4][4];
#pragma unroll
    for (int i = 0; i < 4; i++)
#pragma unroll
        for (int j = 0; j < 4; j++) acc[i][j] = (f32x4){0.f, 0.f, 0.f, 0.f};

    const int NT = DIMn / 32;  // 32
    STAGE(0, 0);
    STAGE(1, 1);
    STAGE(2, 2);

    int buf = 0;
    for (int tt = 0; tt < NT; ++tt) {
        if (tt < NT - 2)       asm volatile("s_waitcnt vmcnt(8)" ::: "memory");
        else if (tt == NT - 2) asm volatile("s_waitcnt vmcnt(4)" ::: "memory");
        else                   asm volatile("s_waitcnt vmcnt(0)" ::: "memory");
        barrier_nodrain();

        bf16x8 a[4], b[4];
#pragma unroll
        for (int i = 0; i < 4; i++)
            a[i] = ldfrag(&Abf[buf][((wm * 4 + i) * 4 + quad) * 128 + l15 * 8]);
#pragma unroll
        for (int j = 0; j < 4; j++)
            b[j] = ldfrag(&Bbf[buf][((wn * 4 + j) * 4 + quad) * 128 + l15 * 8]);
#pragma unroll
        for (int i = 0; i < 4; i++)
#pragma unroll
            for (int j = 0; j < 4; j++)
                acc[i][j] = __builtin_amdgcn_mfma_f32_16x16x32_bf16(a[i], b[j], acc[i][j], 0, 0, 0);

        asm volatile("s_waitcnt lgkmcnt(0)" ::: "memory");
        barrier_nodrain();
        if (tt + 3 < NT) STAGE(tt + 3, buf);  // refill just-freed slot
        buf = (buf == 2) ? 0 : buf + 1;
    }

    float bv[4];
#pragma unroll
    for (int j = 0; j < 4; j++) bv[j] = bias[n0 + wn * 64 + j * 16 + l15];

#pragma unroll
    for (int i = 0; i < 4; i++)
#pragma unroll
        for (int j = 0; j < 4; j++) {
            const int n = n0 + wn * 64 + j * 16 + l15;
#pragma unroll
            for (int r = 0; r < 4; r++) {
                const int m = m0 + wm * 64 + i * 16 + quad * 4 + r;
                out[(size_t)m * DIMn + n] = acc[i][j][r] + bv[j];
            }
        }
}

// ---------------------------------------------------------------------------
// MFMA flash attention (no max-tracking), pipelined depth-2.
// Per wave per j-tile: 2 K + 2 V global_load_lds = 4 vmcnt ops -> vmcnt(4).
// Mask (8 KB = 2048 ints) is staged ONCE in the prologue with plain coalesced
// int4 loads + LDS writes into Kbf[0] (256 threads x 2 int4 = 8 KB exactly),
// then bit-packed into 4 u32 registers per lane; the main loop issues NO
// extra VMEM ops. LDS = 32 KB K/V dbuf + 8 KB swizzled Ps = 40 KB.
// ---------------------------------------------------------------------------
__global__ __launch_bounds__(256) void attn_mfma(
    const u16* __restrict__ Qw, const u16* __restrict__ Kw,
    const u16* __restrict__ VwT, const int* __restrict__ mask,
    const int* __restrict__ tstat, u16* __restrict__ Aw)
{
    __shared__ __align__(16) u16 Kbf[2][32 * 128];  // 2 x 8 KB chunked
    __shared__ __align__(16) u16 Vbf[2][32 * 128];  // 2 x 8 KB chunked
    __shared__ __align__(16) u16 Ps[64 * 64];       // 8 KB, XOR-swizzled rows

    const int f = blockIdx.x;
    const int xcd = f & 7, q = f >> 3;
    const int p = xcd * 4 + (q >> 5);
    const int qt = q & 31;
    const int b = p >> 4, h = p & 15;
    const int q0 = qt * 64;

    const int t = threadIdx.x;
    const int lane = t & 63, wave = t >> 6;
    const int quad = lane >> 4, l15 = lane & 15;
    const bool use_mask = (tstat[0] != 0);
    const size_t slab = (size_t)(b * Hn + h) * Sn * DHn;

    // Staging base pointers (j0-invariant parts)
    const u16* baseK[2];
    const u16* baseV[2];
#pragma unroll
    for (int s = 0; s < 2; s++) {
        const int c = wave * 8 + s * 4 + quad;
        const int rg = c >> 3, qp = c & 7;
        baseK[s] = Kw  + slab + (size_t)(rg * 16 + l15) * DHn + qp * 8;  // + j0*DHn
        baseV[s] = VwT + slab + (size_t)(rg * 16 + l15) * Sn  + qp * 8;  // + j0
    }

    // ---- prologue: stage full 8 KB mask into Kbf[0] with plain loads ----
    {
        const int4* msrc4 = (const int4*)(mask + (size_t)b * Sn);  // 512 int4
        int4* mdst4 = (int4*)&Kbf[0][0];
        mdst4[t]       = msrc4[t];
        mdst4[t + 256] = msrc4[t + 256];
    }
    bf16x8 aq[2];
#pragma unroll
    for (int ks = 0; ks < 2; ks++) {
        union { uint4 u; bf16x8 v; } xx;
        xx.u = *(const uint4*)(Qw + slab + (size_t)(q0 + wave * 16 + l15) * DHn + ks * 32 + quad * 8);
        aq[ks] = xx.v;
    }
    __syncthreads();  // drains vmcnt+lgkmcnt: Q in regs, full mask visible in LDS

    // ---- pack this lane's mask bits: bit k = (mask[k*16 + l15] != 0) ----
    u32 mw0 = 0, mw1 = 0, mw2 = 0, mw3 = 0;
    {
        const int* ml = (const int*)&Kbf[0][0];
#pragma unroll
        for (int k = 0; k < 128; k++) {
            const u32 bit = (ml[k * 16 + l15] != 0) ? 1u : 0u;
            if (k < 32)      mw0 |= bit << k;
            else if (k < 64) mw1 |= bit << (k - 32);
            else if (k < 96) mw2 |= bit << (k - 64);
            else             mw3 |= bit << (k - 96);
        }
    }
    __syncthreads();  // all pack reads retired before Kbf[0] is reused

    auto STAGE = [&](int tt, int buf) {
        const int j0 = tt * 64;
#pragma unroll
        for (int s = 0; s < 2; s++) {
            gl_lds16(baseK[s] + (size_t)j0 * DHn, &Kbf[buf][(wave * 8 + s * 4) * 128]);
            gl_lds16(baseV[s] + j0,               &Vbf[buf][(wave * 8 + s * 4) * 128]);
        }
    };

    float lsum[4] = {0.f, 0.f, 0.f, 0.f};
    f32x4 O[4];
#pragma unroll
    for (int dt = 0; dt < 4; dt++) O[dt] = (f32x4){0.f, 0.f, 0.f, 0.f};

    const int NT = Sn / 64;  // 32
    STAGE(0, 0);
    STAGE(1, 1);

#pragma unroll 2
    for (int tt = 0; tt < NT; ++tt) {
        const int buf = tt & 1;
        if (tt < NT - 1) asm volatile("s_waitcnt vmcnt(4)" ::: "memory");
        else             asm volatile("s_waitcnt vmcnt(0)" ::: "memory");
        barrier_nodrain();  // tile tt (K and V) visible to all waves

        // ---- S = Q K^T ----
        f32x4 s[4];
#pragma unroll
        for (int ct = 0; ct < 4; ct++) s[ct] = (f32x4){0.f, 0.f, 0.f, 0.f};
#pragma unroll
        for (int ct = 0; ct < 4; ct++)
#pragma unroll
            for (int ks = 0; ks < 2; ks++) {
                const bf16x8 bk = ldfrag(&Kbf[buf][(ct * 8 + ks * 4 + quad) * 128 + l15 * 8]);
                s[ct] = __builtin_amdgcn_mfma_f32_16x16x32_bf16(aq[ks], bk, s[ct], 0, 0, 0);
            }

        // ---- mask bits for this tile: k = tt*4 + ct ----
        const int wsel = tt >> 3;
        const u32 cw = (wsel == 0) ? mw0 : (wsel == 1) ? mw1 : (wsel == 2) ? mw2 : mw3;
        const int sh = (tt & 7) * 4;
        u32 mc[4];
#pragma unroll
        for (int ct = 0; ct < 4; ct++)
            mc[ct] = use_mask ? ((cw >> (sh + ct)) & 1u) : 1u;

        // ---- P = exp(mask ? s/64 : -1e9); accumulate l; stash P ----
#pragma unroll
        for (int ct = 0; ct < 4; ct++)
#pragma unroll
            for (int r = 0; r < 4; r++) {
                const float sv = mc[ct] ? s[ct][r] * (1.0f / 64.0f) : -1e9f;
                const float pp = __expf(sv);
                lsum[r] += pp;
                const int prow = wave * 16 + quad * 4 + r;
                Ps[prow * 64 + ((ct * 16 + l15) ^ ((prow & 7) << 3))] = f2bf(pp);
            }
        asm volatile("s_waitcnt lgkmcnt(0)" ::: "memory");  // wave-private band

        // ---- O += P V ----
        bf16x8 pa[2];
        const int rrow = wave * 16 + l15;
#pragma unroll
        for (int kc = 0; kc < 2; kc++)
            pa[kc] = ldfrag(&Ps[rrow * 64 + ((kc * 32 + quad * 8) ^ ((l15 & 7) << 3))]);
#pragma unroll
        for (int dt = 0; dt < 4; dt++)
#pragma unroll
            for (int kc = 0; kc < 2; kc++) {
                const bf16x8 bvv = ldfrag(&Vbf[buf][(dt * 8 + kc * 4 + quad) * 128 + l15 * 8]);
                O[dt] = __builtin_amdgcn_mfma_f32_16x16x32_bf16(pa[kc], bvv, O[dt], 0, 0, 0);
            }

        asm volatile("s_waitcnt lgkmcnt(0)" ::: "memory");  // reads done before free
        barrier_nodrain();  // all waves done reading Kbf/Vbf[buf]
        if (tt + 2 < NT) STAGE(tt + 2, buf);
    }

    // ---- reduce l across the 16 column-lanes ----
#pragma unroll
    for (int r = 0; r < 4; r++) {
#pragma unroll
        for (int off = 1; off < 16; off <<= 1) lsum[r] += __shfl_xor(lsum[r], off);
    }

    // ---- epilogue: normalize, overwrite the Q slab ([b,h,s,d]) ----
#pragma unroll
    for (int r = 0; r < 4; r++) {
        const float linv = 1.0f / fmaxf(lsum[r], 1e-30f);
        const int srow = q0 + wave * 16 + quad * 4 + r;
#pragma unroll
        for (int dt = 0; dt < 4; dt++)
            Aw[slab + (size_t)srow * DHn + dt * 16 + l15] = f2bf(O[dt][r] * linv);
    }
}

// ---------------------------------------------------------------------------
extern "C" void kernel_launch(void* const* d_in, const int* in_sizes, int n_in,
                              void* d_out, int out_size, void* d_ws, size_t ws_size,
                              hipStream_t stream) {
    const float* query = (const float*)d_in[0];
    const float* key   = (const float*)d_in[1];
    const float* value = (const float*)d_in[2];
    const int*   pmask = (const int*)d_in[3];
    const int*   tstat = (const int*)d_in[4];
    const float* Wq  = (const float*)d_in[5];
    const float* bq  = (const float*)d_in[6];
    const float* Wk  = (const float*)d_in[7];
    const float* bk  = (const float*)d_in[8];
    const float* Wv  = (const float*)d_in[9];
    const float* bv  = (const float*)d_in[10];
    const float* Wf  = (const float*)d_in[11];
    const float* bfb = (const float*)d_in[12];
    float* outp = (float*)d_out;

    // ws (32 MB): Qw(8, attn-out alias) | Kw(8) | VwT(8) | Wt 4x2MB(8)
    const size_t NT = (size_t)Bn * Sn * DIMn;
    u16* Qw  = (u16*)d_ws;
    u16* Kw  = Qw + NT;
    u16* VwT = Kw + NT;
    u16* Wt  = VwT + NT;
    const size_t WSZ = (size_t)DIMn * DIMn;

    prep_weights<<<dim3(16, 16, 4), 256, 0, stream>>>(Wq, Wk, Wv, Wf, Wt);

    gemm_qkv<<<768, 256, 0, stream>>>(query, key, value, Wt, bq, bk, bv, Qw, Kw, VwT);

    attn_mfma<<<1024, 256, 0, stream>>>(Qw, Kw, VwT, pmask, tstat, Qw);

    gemm_final<<<256, 256, 0, stream>>>(Qw, Wt + 3 * WSZ, bfb, outp);
}

// Round 4
// 277.847 us; speedup vs baseline: 1.1071x; 1.1071x over previous
//
#include <hip/hip_runtime.h>

// Problem: B=2, S=2048, DIM=1024, H=16, DH=64. I/O fp32; internals bf16 MFMA.
#define Bn   2
#define Sn   2048
#define DIMn 1024
#define Hn   16
#define DHn  64

typedef unsigned short u16;
typedef unsigned int   u32;

typedef __attribute__((ext_vector_type(8))) __bf16 bf16x8;
typedef __attribute__((ext_vector_type(8))) float  f32x8v;
typedef __attribute__((ext_vector_type(4))) float  f32x4;

__device__ __forceinline__ u16 f2bf(float f) {
    union { float f; u32 u; } v; v.f = f;
    u32 r = v.u + 0x7fffu + ((v.u >> 16) & 1u);  // RNE
    return (u16)(r >> 16);
}
__device__ __forceinline__ bf16x8 ldfrag(const u16* p) {
    union { uint4 u; bf16x8 v; } x;
    x.u = *(const uint4*)p;
    return x.v;
}
__device__ __forceinline__ uint4 pack8(const u16 h[8]) {
    uint4 r;
    r.x = (u32)h[0] | ((u32)h[1] << 16);
    r.y = (u32)h[2] | ((u32)h[3] << 16);
    r.z = (u32)h[4] | ((u32)h[5] << 16);
    r.w = (u32)h[6] | ((u32)h[7] << 16);
    return r;
}
// async 16B global->LDS: lds dest = wave-uniform base + lane*16; global src PER-LANE
__device__ __forceinline__ void gl_lds16(const void* g, void* l) {
    __builtin_amdgcn_global_load_lds(
        (const __attribute__((address_space(1))) void*)g,
        (__attribute__((address_space(3))) void*)l, 16, 0, 0);
}
// raw barrier with compiler-level memory fences on both sides (no vmcnt drain)
__device__ __forceinline__ void barrier_nodrain() {
    asm volatile("" ::: "memory");
    __builtin_amdgcn_s_barrier();
    asm volatile("" ::: "memory");
}

// ---------------------------------------------------------------------------
// Prep: transpose+convert fp32 weights [k][n] -> bf16 CHUNK-TILED Wt.
// Layout: off(z,X,T,o,lane=quad*16+l15,e) =
//   ((((z*8+X)*32+T)*8+o)*64 + quad*16+l15)*8 + e
// holding element (n = X*128+o*16+l15, k = T*32+quad*8+e).
// Every GEMM staging op then reads 1KB CONTIGUOUS (8 cache lines).
// ---------------------------------------------------------------------------
__global__ __launch_bounds__(256) void prep_weights(
    const float* __restrict__ Wq, const float* __restrict__ Wk,
    const float* __restrict__ Wv, const float* __restrict__ Wf,
    u16* __restrict__ Wt)
{
    __shared__ __align__(16) float tile[64][68];
    const float* W = (blockIdx.z == 0) ? Wq : (blockIdx.z == 1) ? Wk
                   : (blockIdx.z == 2) ? Wv : Wf;
    const int t = threadIdx.x;
    const int n0 = blockIdx.x * 64, k0 = blockIdx.y * 64;
    const int rr = t >> 4, cc = (t & 15) * 4;
#pragma unroll
    for (int i = 0; i < 4; i++)
        *(float4*)&tile[rr + 16 * i][cc] =
            *(const float4*)(W + (size_t)(k0 + rr + 16 * i) * DIMn + n0 + cc);
    __syncthreads();
#pragma unroll
    for (int e = 0; e < 2; e++) {
        const int ci = 2 * t + e;
        const int nn = ci >> 3, kc = ci & 7;
        const int n = n0 + nn, k = k0 + kc * 8;
        u16 h[8];
#pragma unroll
        for (int j = 0; j < 8; j++) h[j] = f2bf(tile[kc * 8 + j][nn]);
        const int X = n >> 7, o = (n >> 4) & 7, l15 = n & 15;
        const int T = k >> 5, quad = (k >> 3) & 3;
        const size_t off =
            ((((size_t)(blockIdx.z * 8 + X) * 32 + T) * 8 + o) * 64 + quad * 16 + l15) * 8;
        *(uint4*)(Wt + off) = pack8(h);
    }
}

// ---------------------------------------------------------------------------
// Fused QKV GEMM. All staging ops now read 8 FULL cache lines:
//  - A (fp32): op = 8 rows x 128B, per-lane source XOR-swizzled (c8^r8) so the
//    linear LDS tile [128 rows][32 f32] reads back conflict-light.
//  - B: chunk-tiled Wt, 1KB contiguous per op.
// Depth-2 pipeline, counted vmcnt(6), raw barriers (unchanged accounting).
// Epilogue writes Q in [b,h,s,d]; K and V in ATTN-CHUNK-TILED layouts.
// ---------------------------------------------------------------------------
__global__ __launch_bounds__(256) void gemm_qkv(
    const float* __restrict__ Aq, const float* __restrict__ Ak,
    const float* __restrict__ Av, const u16* __restrict__ Wt,
    const float* __restrict__ bqp, const float* __restrict__ bkp,
    const float* __restrict__ bvp, u16* __restrict__ Qw,
    u16* __restrict__ Kw, u16* __restrict__ VwT)
{
    __shared__ union {
        struct { __align__(16) float Afp[2][4096];   // 2 x 16 KB: [128 rows][32 f32]
                 __align__(16) u16   Bbf[2][4096]; } s;  // 2 x 8 KB, chunked
        __align__(16) u16 Ep[32][144];               // epilogue staging
    } L;

    // ---- XCD-aware swizzle: f = xcd + 8*(x + 8*(yi + 4*z)) ----
    const int f = blockIdx.x;
    const int xcd = f & 7;
    const int q = f >> 3;
    const int z = q >> 5;
    const int rem = q & 31;
    const int yi = rem >> 3, x = rem & 7;
    const int y = xcd * 4 + yi;
    const int m0 = y * 128, n0 = x * 128;

    const float* A    = (z == 0) ? Aq  : (z == 1) ? Ak  : Av;
    const float* bias = (z == 0) ? bqp : (z == 1) ? bkp : bvp;

    const int t = threadIdx.x;
    const int lane = t & 63, wave = t >> 6;
    const int quad = lane >> 4, l15 = lane & 15;
    const int wm = wave >> 1, wn = wave & 1;

    // A staging: op o = wave*4+s covers rows m0+o*8+r8, 128B k-window.
    // Lane (r8,c8) fetches col-slot (c8^r8) -> LDS linear -> swizzled read.
    const int r8 = lane >> 3, c8 = lane & 7;
    const float* baseA[4];
#pragma unroll
    for (int s = 0; s < 4; s++)
        baseA[s] = A + (size_t)(m0 + (wave * 4 + s) * 8 + r8) * DIMn + ((c8 ^ r8) << 2);
    // B staging: chunk-tiled Wt, op o = wave*2+s, 1KB contiguous.
    const u16* baseB[2];
#pragma unroll
    for (int s = 0; s < 2; s++)
        baseB[s] = Wt + ((size_t)((z * 8 + x) * 32) * 8 + (wave * 2 + s)) * 512 + lane * 8;

    auto STAGE = [&](int tt, int buf) {
#pragma unroll
        for (int s = 0; s < 4; s++)
            gl_lds16(baseA[s] + tt * 32, &L.s.Afp[buf][(wave * 4 + s) * 256]);
#pragma unroll
        for (int s = 0; s < 2; s++)
            gl_lds16(baseB[s] + (size_t)tt * 4096, &L.s.Bbf[buf][(wave * 8 + s * 4) * 128]);
    };

    f32x4 acc[4][4];
#pragma unroll
    for (int i = 0; i < 4; i++)
#pragma unroll
        for (int j = 0; j < 4; j++) acc[i][j] = (f32x4){0.f, 0.f, 0.f, 0.f};

    const int NT = DIMn / 32;  // 32
    STAGE(0, 0);
    STAGE(1, 1);

#pragma unroll 2
    for (int tt = 0; tt < NT; ++tt) {
        const int buf = tt & 1;
        if (tt < NT - 1) asm volatile("s_waitcnt vmcnt(6)" ::: "memory");
        else             asm volatile("s_waitcnt vmcnt(0)" ::: "memory");
        barrier_nodrain();

        bf16x8 a[4], b[4];
#pragma unroll
        for (int i = 0; i < 4; i++) {
            const int lr = wm * 64 + i * 16 + l15;
            const int rx = lr & 7;
            union { struct { f32x4 lo, hi; } p; f32x8v v; } u;
            u.p.lo = *(const f32x4*)&L.s.Afp[buf][lr * 32 + (((quad * 2 + 0) ^ rx) << 2)];
            u.p.hi = *(const f32x4*)&L.s.Afp[buf][lr * 32 + (((quad * 2 + 1) ^ rx) << 2)];
            a[i] = __builtin_convertvector(u.v, bf16x8);
        }
#pragma unroll
        for (int j = 0; j < 4; j++)
            b[j] = ldfrag(&L.s.Bbf[buf][((wn * 4 + j) * 4 + quad) * 128 + l15 * 8]);
#pragma unroll
        for (int i = 0; i < 4; i++)
#pragma unroll
            for (int j = 0; j < 4; j++)
                acc[i][j] = __builtin_amdgcn_mfma_f32_16x16x32_bf16(a[i], b[j], acc[i][j], 0, 0, 0);

        asm volatile("s_waitcnt lgkmcnt(0)" ::: "memory");
        barrier_nodrain();
        if (tt + 2 < NT) STAGE(tt + 2, buf);
    }

    float bv[4];
#pragma unroll
    for (int j = 0; j < 4; j++) bv[j] = bias[n0 + wn * 64 + j * 16 + l15];

    const int bb = y >> 4;

    if (z == 0) {
        // ---- Q: [b,h,s,d], phase over i ----
#pragma unroll
        for (int i = 0; i < 4; i++) {
            __syncthreads();
#pragma unroll
            for (int j = 0; j < 4; j++)
#pragma unroll
                for (int r = 0; r < 4; r++)
                    L.Ep[wm * 16 + quad * 4 + r][wn * 64 + j * 16 + l15] =
                        f2bf(acc[i][j][r] + bv[j]);
            __syncthreads();
#pragma unroll
            for (int e = 0; e < 2; e++) {
                const int ci = t + 256 * e;
                const int row = ci >> 4, c = ci & 15;
                const uint4 v = *(const uint4*)&L.Ep[row][c * 8];
                const int m = m0 + (row >> 4) * 64 + i * 16 + (row & 15);
                const int ss = m & 2047;
                const int n = n0 + c * 8;
                const int hh = n >> 6, dd = n & 63;
                *(uint4*)(Qw + ((size_t)(bb * Hn + hh) * Sn + ss) * DHn + dd) = v;
            }
        }
    } else if (z == 1) {
        // ---- K: attn-chunk-tiled; wave-contiguous 1KB stores ----
#pragma unroll
        for (int i = 0; i < 4; i++) {
            __syncthreads();
#pragma unroll
            for (int j = 0; j < 4; j++)
#pragma unroll
                for (int r = 0; r < 4; r++)
                    L.Ep[wm * 16 + quad * 4 + r][wn * 64 + j * 16 + l15] =
                        f2bf(acc[i][j][r] + bv[j]);
            __syncthreads();
#pragma unroll
            for (int e2 = 0; e2 < 2; e2++) {
                const int tid = t + 256 * e2;
                const int l15o = tid & 15;
                const int qo   = (tid >> 4) & 3;
                const int k1   = (tid >> 6) & 1;
                const int c3   = (tid >> 7) & 1;
                const int w    = (tid >> 8) & 1;
                const int c    = c3 * 8 + k1 * 4 + qo;
                const uint4 v = *(const uint4*)&L.Ep[w * 16 + l15o][c * 8];
                const int ss = (m0 & 2047) + w * 64 + i * 16 + l15o;
                const int hh = (n0 + c * 8) >> 6;
                const int jt = ss >> 6;
                const int o  = i * 2 + k1;
                const size_t off =
                    ((((size_t)(bb * Hn + hh) * 32 + jt) * 8 + o) * 64 + qo * 16 + l15o) * 8;
                *(uint4*)(Kw + off) = v;
            }
        }
    } else {
        // ---- V: attn-chunk-tiled (transposed fill), phase over j ----
#pragma unroll
        for (int j = 0; j < 4; j++) {
            __syncthreads();
#pragma unroll
            for (int i = 0; i < 4; i++) {
                u16 h4[4];
#pragma unroll
                for (int r = 0; r < 4; r++) h4[r] = f2bf(acc[i][j][r] + bv[j]);
                uint2 pk;
                pk.x = (u32)h4[0] | ((u32)h4[1] << 16);
                pk.y = (u32)h4[2] | ((u32)h4[3] << 16);
                *(uint2*)&L.Ep[wn * 16 + l15][wm * 64 + i * 16 + quad * 4] = pk;
            }
            __syncthreads();
#pragma unroll
            for (int e2 = 0; e2 < 2; e2++) {
                const int tid = t + 256 * e2;
                const int l15o = tid & 15;
                const int qo   = (tid >> 4) & 3;
                const int k1   = (tid >> 6) & 1;
                const int c3   = (tid >> 7) & 1;
                const int w    = (tid >> 8) & 1;
                const int c    = c3 * 8 + k1 * 4 + qo;
                const uint4 v = *(const uint4*)&L.Ep[w * 16 + l15o][c * 8];
                const int n  = n0 + w * 64 + j * 16 + l15o;
                const int hh = n >> 6;
                const int jt = ((m0 & 2047) >> 6) + c3;
                const int o  = j * 2 + k1;
                const size_t off =
                    ((((size_t)(bb * Hn + hh) * 32 + jt) * 8 + o) * 64 + qo * 16 + l15o) * 8;
                *(uint4*)(VwT + off) = v;
            }
        }
    }
}

// ---------------------------------------------------------------------------
// Final GEMM, depth-3 pipeline. B from chunk-tiled Wt (contiguous 1KB ops).
// A (attn output in [b,h,s,d]) staging unchanged.
// ---------------------------------------------------------------------------
__global__ __launch_bounds__(256) void gemm_final(
    const u16* __restrict__ A, const u16* __restrict__ Bt,
    const float* __restrict__ bias, float* __restrict__ out)
{
    __shared__ __align__(16) u16 Abf[3][32 * 128];  // 3 x 8 KB chunked
    __shared__ __align__(16) u16 Bbf[3][32 * 128];  // 3 x 8 KB chunked

    const int f = blockIdx.x;
    const int xcd = f & 7, q = f >> 3;
    const int y = xcd * 4 + (q >> 3), x = q & 7;
    const int m0 = y * 128, n0 = x * 128;

    const int t = threadIdx.x;
    const int lane = t & 63, wave = t >> 6;
    const int quad = lane >> 4, l15 = lane & 15;
    const int wm = wave >> 1, wn = wave & 1;

    int arow[2], aq[2];
#pragma unroll
    for (int s = 0; s < 2; s++) {
        const int c = wave * 8 + s * 4 + quad;
        arow[s] = (c >> 2) * 16 + l15;  // local m row
        aq[s] = c & 3;
    }
    const u16* baseB[2];
#pragma unroll
    for (int s = 0; s < 2; s++)
        baseB[s] = Bt + ((size_t)(x * 32) * 8 + (wave * 2 + s)) * 512 + lane * 8;

    auto STAGE = [&](int tt, int buf) {
        const int hh = tt >> 1, d64 = (tt & 1) * 32;
#pragma unroll
        for (int s = 0; s < 2; s++) {
            const int m = m0 + arow[s], bb = m >> 11, ss = m & 2047;
            const u16* gp = A + ((size_t)(bb * Hn + hh) * Sn + ss) * DHn + d64 + aq[s] * 8;
            gl_lds16(gp, &Abf[buf][(wave * 8 + s * 4) * 128]);
        }
#pragma unroll
        for (int s = 0; s < 2; s++)
            gl_lds16(baseB[s] + (size_t)tt * 4096, &Bbf[buf][(wave * 8 + s * 4) * 128]);
    };

    f32x4 acc[4][4];
#pragma unroll
    for (int i = 0; i < 4; i++)
#pragma unroll
        for (int j = 0; j < 4; j++) acc[i][j] = (f32x4){0.f, 0.f, 0.f, 0.f};

    const int NT = DIMn / 32;  // 32
    STAGE(0, 0);
    STAGE(1, 1);
    STAGE(2, 2);

    int buf = 0;
    for (int tt = 0; tt < NT; ++tt) {
        if (tt < NT - 2)       asm volatile("s_waitcnt vmcnt(8)" ::: "memory");
        else if (tt == NT - 2) asm volatile("s_waitcnt vmcnt(4)" ::: "memory");
        else                   asm volatile("s_waitcnt vmcnt(0)" ::: "memory");
        barrier_nodrain();

        bf16x8 a[4], b[4];
#pragma unroll
        for (int i = 0; i < 4; i++)
            a[i] = ldfrag(&Abf[buf][((wm * 4 + i) * 4 + quad) * 128 + l15 * 8]);
#pragma unroll
        for (int j = 0; j < 4; j++)
            b[j] = ldfrag(&Bbf[buf][((wn * 4 + j) * 4 + quad) * 128 + l15 * 8]);
#pragma unroll
        for (int i = 0; i < 4; i++)
#pragma unroll
            for (int j = 0; j < 4; j++)
                acc[i][j] = __builtin_amdgcn_mfma_f32_16x16x32_bf16(a[i], b[j], acc[i][j], 0, 0, 0);

        asm volatile("s_waitcnt lgkmcnt(0)" ::: "memory");
        barrier_nodrain();
        if (tt + 3 < NT) STAGE(tt + 3, buf);
        buf = (buf == 2) ? 0 : buf + 1;
    }

    float bv[4];
#pragma unroll
    for (int j = 0; j < 4; j++) bv[j] = bias[n0 + wn * 64 + j * 16 + l15];

#pragma unroll
    for (int i = 0; i < 4; i++)
#pragma unroll
        for (int j = 0; j < 4; j++) {
            const int n = n0 + wn * 64 + j * 16 + l15;
#pragma unroll
            for (int r = 0; r < 4; r++) {
                const int m = m0 + wm * 64 + i * 16 + quad * 4 + r;
                out[(size_t)m * DIMn + n] = acc[i][j][r] + bv[j];
            }
        }
}

// ---------------------------------------------------------------------------
// MFMA flash attention. K/V now chunk-tiled -> staging ops are 1KB contiguous
// (8 lines vs 16 half-lines). Depth-2 pipeline, vmcnt(4). Mask staged in the
// prologue with plain int4 loads, bit-packed per lane. Epilogue restages O
// through Ps (plain layout) for uint4 row-contiguous stores.
// ---------------------------------------------------------------------------
__global__ __launch_bounds__(256) void attn_mfma(
    const u16* __restrict__ Qw, const u16* __restrict__ Kw,
    const u16* __restrict__ VwT, const int* __restrict__ mask,
    const int* __restrict__ tstat, u16* __restrict__ Aw)
{
    __shared__ __align__(16) u16 Kbf[2][32 * 128];  // 2 x 8 KB chunked
    __shared__ __align__(16) u16 Vbf[2][32 * 128];  // 2 x 8 KB chunked
    __shared__ __align__(16) u16 Ps[64 * 64];       // 8 KB, XOR-swizzled in loop

    const int f = blockIdx.x;
    const int xcd = f & 7, q = f >> 3;
    const int p = xcd * 4 + (q >> 5);
    const int qt = q & 31;
    const int b = p >> 4, h = p & 15;
    const int q0 = qt * 64;

    const int t = threadIdx.x;
    const int lane = t & 63, wave = t >> 6;
    const int quad = lane >> 4, l15 = lane & 15;
    const bool use_mask = (tstat[0] != 0);
    const size_t slab = (size_t)(b * Hn + h) * Sn * DHn;

    // Tiled K/V staging bases: head slab = 32 tiles x 8 chunks x 512 u16
    const size_t hbase = (size_t)(b * Hn + h) * 32 * 8 * 512;
    const u16* baseK[2];
    const u16* baseV[2];
#pragma unroll
    for (int s = 0; s < 2; s++) {
        const int o = wave * 2 + s;
        baseK[s] = Kw  + hbase + (size_t)o * 512 + lane * 8;
        baseV[s] = VwT + hbase + (size_t)o * 512 + lane * 8;
    }

    // ---- prologue: stage full 8 KB mask into Kbf[0] with plain loads ----
    {
        const int4* msrc4 = (const int4*)(mask + (size_t)b * Sn);  // 512 int4
        int4* mdst4 = (int4*)&Kbf[0][0];
        mdst4[t]       = msrc4[t];
        mdst4[t + 256] = msrc4[t + 256];
    }
    bf16x8 aq[2];
#pragma unroll
    for (int ks = 0; ks < 2; ks++) {
        union { uint4 u; bf16x8 v; } xx;
        xx.u = *(const uint4*)(Qw + slab + (size_t)(q0 + wave * 16 + l15) * DHn + ks * 32 + quad * 8);
        aq[ks] = xx.v;
    }
    __syncthreads();  // Q in regs, full mask visible in LDS

    // ---- pack this lane's mask bits: bit k = (mask[k*16 + l15] != 0) ----
    u32 mw0 = 0, mw1 = 0, mw2 = 0, mw3 = 0;
    {
        const int* ml = (const int*)&Kbf[0][0];
#pragma unroll
        for (int k = 0; k < 128; k++) {
            const u32 bit = (ml[k * 16 + l15] != 0) ? 1u : 0u;
            if (k < 32)      mw0 |= bit << k;
            else if (k < 64) mw1 |= bit << (k - 32);
            else if (k < 96) mw2 |= bit << (k - 64);
            else             mw3 |= bit << (k - 96);
        }
    }
    __syncthreads();  // pack reads retired before Kbf[0] reuse

    auto STAGE = [&](int tt, int buf) {
#pragma unroll
        for (int s = 0; s < 2; s++) {
            gl_lds16(baseK[s] + (size_t)tt * 4096, &Kbf[buf][(wave * 8 + s * 4) * 128]);
            gl_lds16(baseV[s] + (size_t)tt * 4096, &Vbf[buf][(wave * 8 + s * 4) * 128]);
        }
    };

    float lsum[4] = {0.f, 0.f, 0.f, 0.f};
    f32x4 O[4];
#pragma unroll
    for (int dt = 0; dt < 4; dt++) O[dt] = (f32x4){0.f, 0.f, 0.f, 0.f};

    const int NT = Sn / 64;  // 32
    STAGE(0, 0);
    STAGE(1, 1);

#pragma unroll 2
    for (int tt = 0; tt < NT; ++tt) {
        const int buf = tt & 1;
        if (tt < NT - 1) asm volatile("s_waitcnt vmcnt(4)" ::: "memory");
        else             asm volatile("s_waitcnt vmcnt(0)" ::: "memory");
        barrier_nodrain();

        // ---- S = Q K^T ----
        f32x4 s[4];
#pragma unroll
        for (int ct = 0; ct < 4; ct++) s[ct] = (f32x4){0.f, 0.f, 0.f, 0.f};
#pragma unroll
        for (int ct = 0; ct < 4; ct++)
#pragma unroll
            for (int ks = 0; ks < 2; ks++) {
                const bf16x8 bk = ldfrag(&Kbf[buf][(ct * 8 + ks * 4 + quad) * 128 + l15 * 8]);
                s[ct] = __builtin_amdgcn_mfma_f32_16x16x32_bf16(aq[ks], bk, s[ct], 0, 0, 0);
            }

        // ---- mask bits for this tile: k = tt*4 + ct ----
        const int wsel = tt >> 3;
        const u32 cw = (wsel == 0) ? mw0 : (wsel == 1) ? mw1 : (wsel == 2) ? mw2 : mw3;
        const int sh = (tt & 7) * 4;
        u32 mc[4];
#pragma unroll
        for (int ct = 0; ct < 4; ct++)
            mc[ct] = use_mask ? ((cw >> (sh + ct)) & 1u) : 1u;

        // ---- P = exp(mask ? s/64 : -1e9); accumulate l; stash P ----
#pragma unroll
        for (int ct = 0; ct < 4; ct++)
#pragma unroll
            for (int r = 0; r < 4; r++) {
                const float sv = mc[ct] ? s[ct][r] * (1.0f / 64.0f) : -1e9f;
                const float pp = __expf(sv);
                lsum[r] += pp;
                const int prow = wave * 16 + quad * 4 + r;
                Ps[prow * 64 + ((ct * 16 + l15) ^ ((prow & 7) << 3))] = f2bf(pp);
            }
        asm volatile("s_waitcnt lgkmcnt(0)" ::: "memory");  // wave-private band

        // ---- O += P V ----
        bf16x8 pa[2];
        const int rrow = wave * 16 + l15;
#pragma unroll
        for (int kc = 0; kc < 2; kc++)
            pa[kc] = ldfrag(&Ps[rrow * 64 + ((kc * 32 + quad * 8) ^ ((l15 & 7) << 3))]);
#pragma unroll
        for (int dt = 0; dt < 4; dt++)
#pragma unroll
            for (int kc = 0; kc < 2; kc++) {
                const bf16x8 bvv = ldfrag(&Vbf[buf][(dt * 8 + kc * 4 + quad) * 128 + l15 * 8]);
                O[dt] = __builtin_amdgcn_mfma_f32_16x16x32_bf16(pa[kc], bvv, O[dt], 0, 0, 0);
            }

        asm volatile("s_waitcnt lgkmcnt(0)" ::: "memory");
        barrier_nodrain();
        if (tt + 2 < NT) STAGE(tt + 2, buf);
    }

    // ---- reduce l across the 16 column-lanes ----
#pragma unroll
    for (int r = 0; r < 4; r++) {
#pragma unroll
        for (int off = 1; off < 16; off <<= 1) lsum[r] += __shfl_xor(lsum[r], off);
    }
    float linv[4];
#pragma unroll
    for (int r = 0; r < 4; r++) linv[r] = 1.0f / fmaxf(lsum[r], 1e-30f);

    // ---- epilogue: restage O in Ps (plain), then uint4 row stores ----
    __syncthreads();
#pragma unroll
    for (int r = 0; r < 4; r++)
#pragma unroll
        for (int dt = 0; dt < 4; dt++)
            Ps[(wave * 16 + quad * 4 + r) * 64 + dt * 16 + l15] = f2bf(O[dt][r] * linv[r]);
    __syncthreads();
#pragma unroll
    for (int e2 = 0; e2 < 2; e2++) {
        const int tid = t + 256 * e2;
        const int lr = tid >> 3, c16 = tid & 7;
        const uint4 v = *(const uint4*)&Ps[lr * 64 + c16 * 8];
        *(uint4*)(Aw + slab + (size_t)(q0 + lr) * DHn + c16 * 8) = v;
    }
}

// ---------------------------------------------------------------------------
extern "C" void kernel_launch(void* const* d_in, const int* in_sizes, int n_in,
                              void* d_out, int out_size, void* d_ws, size_t ws_size,
                              hipStream_t stream) {
    const float* query = (const float*)d_in[0];
    const float* key   = (const float*)d_in[1];
    const float* value = (const float*)d_in[2];
    const int*   pmask = (const int*)d_in[3];
    const int*   tstat = (const int*)d_in[4];
    const float* Wq  = (const float*)d_in[5];
    const float* bq  = (const float*)d_in[6];
    const float* Wk  = (const float*)d_in[7];
    const float* bk  = (const float*)d_in[8];
    const float* Wv  = (const float*)d_in[9];
    const float* bv  = (const float*)d_in[10];
    const float* Wf  = (const float*)d_in[11];
    const float* bfb = (const float*)d_in[12];
    float* outp = (float*)d_out;

    // ws (32 MB): Qw(8, attn-out alias) | Kw tiled(8) | VwT tiled(8) | Wt tiled 4x2MB(8)
    const size_t NT = (size_t)Bn * Sn * DIMn;
    u16* Qw  = (u16*)d_ws;
    u16* Kw  = Qw + NT;
    u16* VwT = Kw + NT;
    u16* Wt  = VwT + NT;
    const size_t WSZ = (size_t)DIMn * DIMn;

    prep_weights<<<dim3(16, 16, 4), 256, 0, stream>>>(Wq, Wk, Wv, Wf, Wt);

    gemm_qkv<<<768, 256, 0, stream>>>(query, key, value, Wt, bq, bk, bv, Qw, Kw, VwT);

    attn_mfma<<<1024, 256, 0, stream>>>(Qw, Kw, VwT, pmask, tstat, Qw);

    gemm_final<<<256, 256, 0, stream>>>(Qw, Wt + 3 * WSZ, bfb, outp);
}